// Round 8
// baseline (117.005 us; speedup 1.0000x reference)
//
#include <hip/hip_runtime.h>
#include <stdint.h>
#include <math.h>

typedef short bf16x8 __attribute__((ext_vector_type(8)));
typedef float f32x16 __attribute__((ext_vector_type(16)));
typedef unsigned int uint4v __attribute__((ext_vector_type(4)));

#define GAS __attribute__((address_space(1)))
#define LAS __attribute__((address_space(3)))

#define CDIM 128
#define NQ   4096
#define NK   16384
#define QT   128         // queries per block (4 waves x 32)
#define KTILE 32
#define LOG2E 1.4426950408889634f

__device__ __forceinline__ unsigned short f2bf(float f) {
    unsigned int u = __builtin_bit_cast(unsigned int, f);
    u = (u + 0x7fffu + ((u >> 16) & 1u)) >> 16;
    return (unsigned short)u;
}

__device__ __forceinline__ void gload_lds16(const void* g, void* l) {
    __builtin_amdgcn_global_load_lds((const GAS unsigned int*)g, (LAS unsigned int*)l, 16, 0, 0);
}

__device__ __forceinline__ unsigned cvtpk(float a, float b) {
    unsigned r;
    asm("v_cvt_pk_bf16_f32 %0, %1, %2" : "=v"(r) : "v"(a), "v"(b));
    return r;
}

// a' = lane<32 ? a : b[lane-32] ; b' = lane<32 ? a[lane+32] : b
__device__ __forceinline__ void swap32(unsigned& a, unsigned& b) {
    asm("v_permlane32_swap_b32 %0, %1" : "+v"(a), "+v"(b));
}

// ---------------- prep_q: Q[q][c] = bf16(log2e * conv2 (x) (feats_t * vt)) ----------------
__global__ void prep_q_kernel(const float* __restrict__ feats_t,
                              const float* __restrict__ v_t,
                              const float* __restrict__ w2,
                              unsigned int* __restrict__ Q32) {
    int idx = blockIdx.x * 256 + threadIdx.x;   // 262144 threads
    int q = idx & 4095, cp = idx >> 12;         // cp = c-pair 0..63
    int y = q >> 6, x = q & 63;
    const float* fb0 = feats_t + (size_t)(cp * 2) * 4096;
    const float* fb1 = fb0 + 4096;
    float wv[9];
#pragma unroll
    for (int i = 0; i < 9; ++i) wv[i] = w2[i];
    float acc0 = 0.f, acc1 = 0.f;
#pragma unroll
    for (int u = 0; u < 3; ++u) {
        int yy = y + u - 1;
        if ((unsigned)yy >= 64u) continue;
#pragma unroll
        for (int v = 0; v < 3; ++v) {
            int xx = x + v - 1;
            if ((unsigned)xx >= 64u) continue;
            float m = wv[u * 3 + v] * v_t[yy * 1024 + xx * 4];
            acc0 += m * fb0[yy * 64 + xx];
            acc1 += m * fb1[yy * 64 + xx];
        }
    }
    Q32[(size_t)q * 64 + cp] =
        (unsigned)f2bf(acc0 * LOG2E) | ((unsigned)f2bf(acc1 * LOG2E) << 16);
}

// ---------------- prep_p: P[c][rk] = fr*vr (f32) ; Vt2 = 32k-tiled bf16 of same ----------------
// Vt2 tile (32 keys, 16B chunks): chunk = jh*128 + c holds V[c][k = tile*32 + jh*8 .. +8)
__global__ void prep_p_kernel(const float* __restrict__ feats_ref,
                              const float* __restrict__ v_ref,
                              float* __restrict__ P,
                              unsigned short* __restrict__ Vt2) {
    int idx = blockIdx.x * 256 + threadIdx.x;   // 2M threads
    int c = idx >> 14, rk = idx & 16383;
    int r = rk >> 12, k4 = rk & 4095, ky = k4 >> 6, kx = k4 & 63;
    float v = feats_ref[idx] * v_ref[r * 65536 + ky * 1024 + kx * 4];
    P[idx] = v;
    Vt2[(size_t)(rk >> 5) * 4096 + (((rk >> 3) & 3) * 128 + c) * 8 + (rk & 7)] = f2bf(v);
}

// ---------------- prep_k2: Kt = 32k-tiled bf16 of conv1 (x) P ----------------
// Kt tile: chunk = cp*32 + rw holds K[rk = tile*32 + rw][c = cp*8 .. +8)
__global__ void prep_k2_kernel(const float* __restrict__ P,
                               const float* __restrict__ w1,
                               unsigned int* __restrict__ K32) {
    int idx = blockIdx.x * 256 + threadIdx.x;   // 1048576 threads
    int rk = idx & 16383, cp2 = idx >> 14;      // cp2 = c-pair 0..63
    int r = rk >> 12, k4 = rk & 4095, ky = k4 >> 6, kx = k4 & 63;
    const float* pb0 = P + (size_t)(cp2 * 2) * NK + r * 4096;
    const float* pb1 = pb0 + NK;
    float wv[9];
#pragma unroll
    for (int i = 0; i < 9; ++i) wv[i] = w1[i];
    float acc0 = 0.f, acc1 = 0.f;
#pragma unroll
    for (int u = 0; u < 3; ++u) {
        int yy = ky + u - 1;
        if ((unsigned)yy >= 64u) continue;
#pragma unroll
        for (int v = 0; v < 3; ++v) {
            int xx = kx + v - 1;
            if ((unsigned)xx >= 64u) continue;
            float w = wv[u * 3 + v];
            acc0 += w * pb0[yy * 64 + xx];
            acc1 += w * pb1[yy * 64 + xx];
        }
    }
    int tile = rk >> 5, rw = rk & 31;
    K32[(size_t)tile * 2048 + ((cp2 >> 2) * 32 + rw) * 4 + (cp2 & 3)] =
        (unsigned)f2bf(acc0) | ((unsigned)f2bf(acc1) << 16);
}

// ---------------- attn: 4 waves x 32q, KTILE=32, 32KB LDS, split-S ILP ----------------
template<int KS>
__launch_bounds__(256, 4)
__global__ void attn_kernel(const unsigned short* __restrict__ Qg,
                            const unsigned short* __restrict__ Kt,
                            const unsigned short* __restrict__ Vt2,
                            float* __restrict__ Opart,
                            float* __restrict__ lpart) {
    constexpr int NITER = (NK / KS) / KTILE;
    __shared__ __align__(16) unsigned short KV[2][2][4096];   // [buf][K/V][8KB tile]

    const int tid = threadIdx.x;
    const int wid = tid >> 6;
    const int lane = tid & 63;
    const int l31 = lane & 31;
    const int lh = lane >> 5;
    const int ks = blockIdx.x & (KS - 1);
    const int qt = blockIdx.x / KS;
    const int q0 = qt * QT + wid * 32;
    const int tile0 = ks * NITER;

    // Q fragments (pre-scaled by log2e): lane holds Q[q0+l31][s*16 + lh*8 + j]
    bf16x8 qf[8];
#pragma unroll
    for (int s = 0; s < 8; ++s)
        qf[s] = *(const bf16x8*)(Qg + (size_t)(q0 + l31) * CDIM + s * 16 + lh * 8);

    f32x16 accO[4];
#pragma unroll
    for (int u = 0; u < 4; ++u)
#pragma unroll
        for (int r = 0; r < 16; ++r) accO[u][r] = 0.f;
    float l_acc = 0.f;

    // staging: pure linear tile copy; 512 chunks each for K and V
#define STAGE(nb, tg)                                                             \
    do {                                                                          \
        _Pragma("unroll") for (int j = 0; j < 2; ++j) {                           \
            int mb = (wid * 2 + j) * 64;                                          \
            gload_lds16(Kt + (size_t)(tg) * 4096 + (mb + lane) * 8,               \
                        &KV[(nb)][0][mb * 8]);                                    \
            gload_lds16(Vt2 + (size_t)(tg) * 4096 + (mb + lane) * 8,              \
                        &KV[(nb)][1][mb * 8]);                                    \
        }                                                                         \
    } while (0)

    int cur = 0;
    STAGE(0, tile0);
    asm volatile("s_waitcnt vmcnt(0)" ::: "memory");
    __syncthreads();

#pragma unroll 1
    for (int it = 0; it < NITER; ++it) {
        if (it + 1 < NITER) STAGE(cur ^ 1, tile0 + it + 1);

        // S^T[k][q] with split accumulators (chains of 4 instead of 8)
        f32x16 Sa, Sb;
#pragma unroll
        for (int r = 0; r < 16; ++r) { Sa[r] = 0.f; Sb[r] = 0.f; }
#pragma unroll
        for (int s = 0; s < 4; ++s) {
            bf16x8 kf = *(const bf16x8*)(&KV[cur][0][((s * 2 + lh) * 32 + l31) * 8]);
            Sa = __builtin_amdgcn_mfma_f32_32x32x16_bf16(kf, qf[s], Sa, 0, 0, 0);
        }
#pragma unroll
        for (int s = 4; s < 8; ++s) {
            bf16x8 kf = *(const bf16x8*)(&KV[cur][0][((s * 2 + lh) * 32 + l31) * 8]);
            Sb = __builtin_amdgcn_mfma_f32_32x32x16_bf16(kf, qf[s], Sb, 0, 0, 0);
        }
        // P = exp2(S) (Q pre-scaled); lane holds 16 k-slots of query q0+l31
        float p[16];
#pragma unroll
        for (int r = 0; r < 16; ++r) {
            p[r] = exp2f(Sa[r] + Sb[r]);
            l_acc += p[r];
        }
        // pack + redistribute into PV B-frag order (verified R5/R7 mapping)
        unsigned w0 = cvtpk(p[0], p[1]),   w1 = cvtpk(p[2], p[3]);
        unsigned w2 = cvtpk(p[4], p[5]),   w3 = cvtpk(p[6], p[7]);
        unsigned w4 = cvtpk(p[8], p[9]),   w5 = cvtpk(p[10], p[11]);
        unsigned w6 = cvtpk(p[12], p[13]), w7 = cvtpk(p[14], p[15]);
        swap32(w0, w2);
        swap32(w1, w3);
        swap32(w4, w6);
        swap32(w5, w7);
        bf16x8 pbA = __builtin_bit_cast(bf16x8, (uint4v){w0, w1, w2, w3});
        bf16x8 pbB = __builtin_bit_cast(bf16x8, (uint4v){w4, w5, w6, w7});
        // O^T += V . P^T  (A = V 32c x 16k slices; 4 independent chains)
#pragma unroll
        for (int u = 0; u < 4; ++u) {
            bf16x8 vfa = *(const bf16x8*)(&KV[cur][1][((lh) * 128 + u * 32 + l31) * 8]);
            accO[u] = __builtin_amdgcn_mfma_f32_32x32x16_bf16(vfa, pbA, accO[u], 0, 0, 0);
            bf16x8 vfb = *(const bf16x8*)(&KV[cur][1][((2 + lh) * 128 + u * 32 + l31) * 8]);
            accO[u] = __builtin_amdgcn_mfma_f32_32x32x16_bf16(vfb, pbB, accO[u], 0, 0, 0);
        }
        asm volatile("s_waitcnt vmcnt(0)" ::: "memory");
        __syncthreads();
        cur ^= 1;
    }
#undef STAGE

    l_acc += __shfl_xor(l_acc, 32);
    if (lane < 32) lpart[ks * NQ + q0 + l31] = l_acc;
#pragma unroll
    for (int u = 0; u < 4; ++u)
#pragma unroll
        for (int r = 0; r < 16; ++r) {
            int c = u * 32 + (r & 3) + 8 * (r >> 2) + 4 * lh;
            Opart[((size_t)(ks * CDIM + c)) * NQ + q0 + l31] = accO[u][r];
        }
}

// ---------------- reduce: out[c][q] = sum_s Opart[s][c][q] / sum_s lpart[s][q] ----------------
template<int KS>
__global__ void reduce_kernel(const float* __restrict__ Opart,
                              const float* __restrict__ lpart,
                              float* __restrict__ out) {
    int i = blockIdx.x * 256 + threadIdx.x;
    int c = i >> 12, q = i & 4095;
    float den = 0.f, o = 0.f;
#pragma unroll
    for (int s = 0; s < KS; ++s) {
        den += lpart[s * NQ + q];
        o += Opart[((size_t)(s * CDIM + c)) * NQ + q];
    }
    out[(size_t)c * NQ + q] = o / den;
}

extern "C" void kernel_launch(void* const* d_in, const int* in_sizes, int n_in,
                              void* d_out, int out_size, void* d_ws, size_t ws_size,
                              hipStream_t stream) {
    (void)in_sizes; (void)n_in; (void)out_size;
    const float* feats_t   = (const float*)d_in[0];
    const float* feats_ref = (const float*)d_in[1];
    const float* v_t       = (const float*)d_in[2];
    const float* v_ref     = (const float*)d_in[3];
    const float* w1        = (const float*)d_in[4];  // conv1 -> K side
    const float* w2        = (const float*)d_in[6];  // conv2 -> Q side
    float* out = (float*)d_out;

    // ws: Q 1MB | Kt 4MB | Vt2 4MB | Opart (KS*2MB) | lpart ; P(f32, 8MB) aliases Opart
    const size_t opart_off = (size_t)(9u << 20);
    const size_t per_split = (size_t)NQ * CDIM * 4;            // 2MB
    const size_t need32 = opart_off + 32 * per_split + 32 * NQ * 4;
    const size_t need16 = opart_off + 16 * per_split + 16 * NQ * 4;
    const size_t need8  = opart_off + 8  * per_split + 8  * NQ * 4;
    if (ws_size < need8) return;

    char* ws = (char*)d_ws;
    unsigned int*   Q   = (unsigned int*)(ws);
    unsigned short* Kt  = (unsigned short*)(ws + (size_t)(1u << 20));
    unsigned short* Vt2 = (unsigned short*)(ws + (size_t)(5u << 20));
    float* Opart = (float*)(ws + opart_off);
    float* P     = Opart;   // consumed by prep_k2 before attn writes Opart

    hipLaunchKernelGGL(prep_q_kernel, dim3(1024), dim3(256), 0, stream, feats_t, v_t, w2, Q);
    hipLaunchKernelGGL(prep_p_kernel, dim3(8192), dim3(256), 0, stream, feats_ref, v_ref, P, Vt2);
    hipLaunchKernelGGL(prep_k2_kernel, dim3(4096), dim3(256), 0, stream, P, w1, (unsigned int*)Kt);

    if (ws_size >= need32) {
        float* lpart = (float*)(ws + opart_off + 32 * per_split);
        hipLaunchKernelGGL(HIP_KERNEL_NAME(attn_kernel<32>), dim3((NQ / QT) * 32), dim3(256), 0,
                           stream, (const unsigned short*)Q, Kt, Vt2, Opart, lpart);
        hipLaunchKernelGGL(HIP_KERNEL_NAME(reduce_kernel<32>), dim3(2048), dim3(256), 0,
                           stream, Opart, lpart, out);
    } else if (ws_size >= need16) {
        float* lpart = (float*)(ws + opart_off + 16 * per_split);
        hipLaunchKernelGGL(HIP_KERNEL_NAME(attn_kernel<16>), dim3((NQ / QT) * 16), dim3(256), 0,
                           stream, (const unsigned short*)Q, Kt, Vt2, Opart, lpart);
        hipLaunchKernelGGL(HIP_KERNEL_NAME(reduce_kernel<16>), dim3(2048), dim3(256), 0,
                           stream, Opart, lpart, out);
    } else {
        float* lpart = (float*)(ws + opart_off + 8 * per_split);
        hipLaunchKernelGGL(HIP_KERNEL_NAME(attn_kernel<8>), dim3((NQ / QT) * 8), dim3(256), 0,
                           stream, (const unsigned short*)Q, Kt, Vt2, Opart, lpart);
        hipLaunchKernelGGL(HIP_KERNEL_NAME(reduce_kernel<8>), dim3(2048), dim3(256), 0,
                           stream, Opart, lpart, out);
    }
}

// Round 9
// 89.146 us; speedup vs baseline: 1.3125x; 1.3125x over previous
//
#include <hip/hip_runtime.h>
#include <stdint.h>
#include <math.h>

typedef short bf16x8 __attribute__((ext_vector_type(8)));
typedef float f32x16 __attribute__((ext_vector_type(16)));
typedef unsigned int uint4v __attribute__((ext_vector_type(4)));

#define GAS __attribute__((address_space(1)))
#define LAS __attribute__((address_space(3)))

#define CDIM 128
#define NQ   4096
#define NK   16384
#define QT   128         // queries per block (4 strips x 32)
#define KTILE 64
#define LOG2E 1.4426950408889634f

__device__ __forceinline__ unsigned short f2bf(float f) {
    unsigned int u = __builtin_bit_cast(unsigned int, f);
    u = (u + 0x7fffu + ((u >> 16) & 1u)) >> 16;
    return (unsigned short)u;
}

__device__ __forceinline__ void gload_lds16(const void* g, void* l) {
    __builtin_amdgcn_global_load_lds((const GAS unsigned int*)g, (LAS unsigned int*)l, 16, 0, 0);
}

__device__ __forceinline__ unsigned cvtpk(float a, float b) {
    unsigned r;
    asm("v_cvt_pk_bf16_f32 %0, %1, %2" : "=v"(r) : "v"(a), "v"(b));
    return r;
}

// a' = lane<32 ? a : b[lane-32] ; b' = lane<32 ? a[lane+32] : b
__device__ __forceinline__ void swap32(unsigned& a, unsigned& b) {
    asm("v_permlane32_swap_b32 %0, %1" : "+v"(a), "+v"(b));
}

// ---------------- prep_q: Q[q][c] = bf16(log2e * conv2 (x) (feats_t * vt)) ----------------
__global__ void prep_q_kernel(const float* __restrict__ feats_t,
                              const float* __restrict__ v_t,
                              const float* __restrict__ w2,
                              unsigned int* __restrict__ Q32) {
    int idx = blockIdx.x * 256 + threadIdx.x;   // 262144 threads
    int q = idx & 4095, cp = idx >> 12;         // cp = c-pair 0..63
    int y = q >> 6, x = q & 63;
    const float* fb0 = feats_t + (size_t)(cp * 2) * 4096;
    const float* fb1 = fb0 + 4096;
    float wv[9];
#pragma unroll
    for (int i = 0; i < 9; ++i) wv[i] = w2[i];
    float acc0 = 0.f, acc1 = 0.f;
#pragma unroll
    for (int u = 0; u < 3; ++u) {
        int yy = y + u - 1;
        if ((unsigned)yy >= 64u) continue;
#pragma unroll
        for (int v = 0; v < 3; ++v) {
            int xx = x + v - 1;
            if ((unsigned)xx >= 64u) continue;
            float m = wv[u * 3 + v] * v_t[yy * 1024 + xx * 4];
            acc0 += m * fb0[yy * 64 + xx];
            acc1 += m * fb1[yy * 64 + xx];
        }
    }
    Q32[(size_t)q * 64 + cp] =
        (unsigned)f2bf(acc0 * LOG2E) | ((unsigned)f2bf(acc1 * LOG2E) << 16);
}

// ---------------- prep_p: P[c][rk] = fr*vr (f32) ; Vt2 = 64k-tiled bf16 of same ----------------
// Vt2 tile (64 keys, 16B chunks): chunk = jh*128 + c holds V[c][k = tile*64 + jh*8 .. +8)
__global__ void prep_p_kernel(const float* __restrict__ feats_ref,
                              const float* __restrict__ v_ref,
                              float* __restrict__ P,
                              unsigned short* __restrict__ Vt2) {
    int idx = blockIdx.x * 256 + threadIdx.x;   // 2M threads
    int c = idx >> 14, rk = idx & 16383;
    int r = rk >> 12, k4 = rk & 4095, ky = k4 >> 6, kx = k4 & 63;
    float v = feats_ref[idx] * v_ref[r * 65536 + ky * 1024 + kx * 4];
    P[idx] = v;
    Vt2[(size_t)(rk >> 6) * 8192 + (((rk >> 3) & 7) * 128 + c) * 8 + (rk & 7)] = f2bf(v);
}

// ---------------- prep_k2: Kt = 64k-tiled bf16 of conv1 (x) P ----------------
// Kt tile: chunk = cp*64 + rw holds K[rk = tile*64 + rw][c = cp*8 .. +8)
__global__ void prep_k2_kernel(const float* __restrict__ P,
                               const float* __restrict__ w1,
                               unsigned int* __restrict__ K32) {
    int idx = blockIdx.x * 256 + threadIdx.x;   // 1048576 threads
    int rk = idx & 16383, cp2 = idx >> 14;      // cp2 = c-pair 0..63
    int r = rk >> 12, k4 = rk & 4095, ky = k4 >> 6, kx = k4 & 63;
    const float* pb0 = P + (size_t)(cp2 * 2) * NK + r * 4096;
    const float* pb1 = pb0 + NK;
    float wv[9];
#pragma unroll
    for (int i = 0; i < 9; ++i) wv[i] = w1[i];
    float acc0 = 0.f, acc1 = 0.f;
#pragma unroll
    for (int u = 0; u < 3; ++u) {
        int yy = ky + u - 1;
        if ((unsigned)yy >= 64u) continue;
#pragma unroll
        for (int v = 0; v < 3; ++v) {
            int xx = kx + v - 1;
            if ((unsigned)xx >= 64u) continue;
            float w = wv[u * 3 + v];
            acc0 += w * pb0[yy * 64 + xx];
            acc1 += w * pb1[yy * 64 + xx];
        }
    }
    int tile = rk >> 6, rw = rk & 63;
    K32[(size_t)tile * 4096 + ((cp2 >> 2) * 64 + rw) * 4 + (cp2 & 3)] =
        (unsigned)f2bf(acc0) | ((unsigned)f2bf(acc1) << 16);
}

// ---------------- attn: 8 waves = 4 q-strips x 2 key-halves, KTILE=64, dbuf ----------------
// waves 0-3: strips 0-3, keys [0,32) of tile; waves 4-7: strips 0-3, keys [32,64).
// LDS merge of the two halves at the end.
template<int KS>
__launch_bounds__(512, 4)
__global__ void attn_kernel(const unsigned short* __restrict__ Qg,
                            const unsigned short* __restrict__ Kt,
                            const unsigned short* __restrict__ Vt2,
                            float* __restrict__ Opart,
                            float* __restrict__ lpart) {
    constexpr int NITER = (NK / KS) / KTILE;
    __shared__ __align__(16) unsigned short KV[2][2][8192];   // [buf][K/V][16KB tile] = 64KB
    __shared__ float lred[4][32];

    const int tid = threadIdx.x;
    const int wid = tid >> 6;
    const int lane = tid & 63;
    const int l31 = lane & 31;
    const int lh = lane >> 5;
    const int strip = wid & 3;
    const int h = wid >> 2;                     // key-half of each tile
    const int ks = blockIdx.x & (KS - 1);
    const int qt = blockIdx.x / KS;
    const int q0 = qt * QT + strip * 32;
    const int tile0 = ks * NITER;

    // Q fragments (pre-scaled by log2e): lane holds Q[q0+l31][s*16 + lh*8 + j]
    bf16x8 qf[8];
#pragma unroll
    for (int s = 0; s < 8; ++s)
        qf[s] = *(const bf16x8*)(Qg + (size_t)(q0 + l31) * CDIM + s * 16 + lh * 8);

    f32x16 accO[4];
#pragma unroll
    for (int u = 0; u < 4; ++u)
#pragma unroll
        for (int r = 0; r < 16; ++r) accO[u][r] = 0.f;
    float l_acc = 0.f;

    // staging: pure linear tile copy; 1024 chunks each for K and V, 512 threads -> 2+2 loads
#define STAGE(nb, tg)                                                             \
    do {                                                                          \
        _Pragma("unroll") for (int j = 0; j < 2; ++j) {                           \
            int mb = (wid * 2 + j) * 64;                                          \
            gload_lds16(Kt + (size_t)(tg) * 8192 + (mb + lane) * 8,               \
                        &KV[(nb)][0][mb * 8]);                                    \
            gload_lds16(Vt2 + (size_t)(tg) * 8192 + (mb + lane) * 8,              \
                        &KV[(nb)][1][mb * 8]);                                    \
        }                                                                         \
    } while (0)

    int cur = 0;
    STAGE(0, tile0);

#pragma unroll 1
    for (int it = 0; it < NITER; ++it) {
        asm volatile("s_waitcnt vmcnt(0)" ::: "memory");   // my stage(it) chunks landed
        __syncthreads();                                   // everyone's landed / prev reads done
        if (it + 1 < NITER) STAGE(cur ^ 1, tile0 + it + 1);  // overlaps with compute below

        // S^T[k][q] over this wave's 32-key half: A = K rows h*32+l31, B = Q
        f32x16 S;
#pragma unroll
        for (int r = 0; r < 16; ++r) S[r] = 0.f;
#pragma unroll
        for (int s = 0; s < 8; ++s) {
            bf16x8 kf = *(const bf16x8*)(&KV[cur][0][((s * 2 + lh) * 64 + h * 32 + l31) * 8]);
            S = __builtin_amdgcn_mfma_f32_32x32x16_bf16(kf, qf[s], S, 0, 0, 0);
        }
        // P = exp2(S) (Q pre-scaled); lane holds 16 k-slots of query q0+l31
        float p[16];
#pragma unroll
        for (int r = 0; r < 16; ++r) { p[r] = exp2f(S[r]); l_acc += p[r]; }
        // pack + redistribute into PV B-frag order (verified R5-R8 mapping)
        unsigned w0 = cvtpk(p[0], p[1]),   w1 = cvtpk(p[2], p[3]);
        unsigned w2 = cvtpk(p[4], p[5]),   w3 = cvtpk(p[6], p[7]);
        unsigned w4 = cvtpk(p[8], p[9]),   w5 = cvtpk(p[10], p[11]);
        unsigned w6 = cvtpk(p[12], p[13]), w7 = cvtpk(p[14], p[15]);
        swap32(w0, w2);
        swap32(w1, w3);
        swap32(w4, w6);
        swap32(w5, w7);
        bf16x8 pbA = __builtin_bit_cast(bf16x8, (uint4v){w0, w1, w2, w3});
        bf16x8 pbB = __builtin_bit_cast(bf16x8, (uint4v){w4, w5, w6, w7});
        // O^T += V . P^T over this wave's key-half (V k-chunks jh = h*4 + {0..3})
#pragma unroll
        for (int u = 0; u < 4; ++u) {
            bf16x8 vfa = *(const bf16x8*)(&KV[cur][1][((h * 4 + lh) * 128 + u * 32 + l31) * 8]);
            accO[u] = __builtin_amdgcn_mfma_f32_32x32x16_bf16(vfa, pbA, accO[u], 0, 0, 0);
            bf16x8 vfb = *(const bf16x8*)(&KV[cur][1][((h * 4 + 2 + lh) * 128 + u * 32 + l31) * 8]);
            accO[u] = __builtin_amdgcn_mfma_f32_32x32x16_bf16(vfb, pbB, accO[u], 0, 0, 0);
        }
        cur ^= 1;
    }
#undef STAGE

    // merge the two key-halves (waves h=1 dump to LDS, waves h=0 add + write out)
    __syncthreads();
    float* mbuf = (float*)&KV[0][0][0];        // 4 strips x 4096 floats = 64KB
    l_acc += __shfl_xor(l_acc, 32);
    if (h == 1) {
        float* sb = mbuf + strip * 4096;
#pragma unroll
        for (int u = 0; u < 4; ++u)
#pragma unroll
            for (int r = 0; r < 16; ++r) {
                int c = u * 32 + (r & 3) + 8 * (r >> 2) + 4 * lh;
                sb[c * 32 + l31] = accO[u][r];
            }
        if (lane < 32) lred[strip][l31] = l_acc;
    }
    __syncthreads();
    if (h == 0) {
        float* sb = mbuf + strip * 4096;
        float lt = l_acc + lred[strip][l31];
        if (lane < 32) lpart[ks * NQ + q0 + l31] = lt;
#pragma unroll
        for (int u = 0; u < 4; ++u)
#pragma unroll
            for (int r = 0; r < 16; ++r) {
                int c = u * 32 + (r & 3) + 8 * (r >> 2) + 4 * lh;
                Opart[((size_t)(ks * CDIM + c)) * NQ + q0 + l31] = accO[u][r] + sb[c * 32 + l31];
            }
    }
}

// ---------------- reduce: out[c][q] = sum_s Opart[s][c][q] / sum_s lpart[s][q] ----------------
template<int KS>
__global__ void reduce_kernel(const float* __restrict__ Opart,
                              const float* __restrict__ lpart,
                              float* __restrict__ out) {
    int i = blockIdx.x * 256 + threadIdx.x;
    int c = i >> 12, q = i & 4095;
    float den = 0.f, o = 0.f;
#pragma unroll
    for (int s = 0; s < KS; ++s) {
        den += lpart[s * NQ + q];
        o += Opart[((size_t)(s * CDIM + c)) * NQ + q];
    }
    out[(size_t)c * NQ + q] = o / den;
}

extern "C" void kernel_launch(void* const* d_in, const int* in_sizes, int n_in,
                              void* d_out, int out_size, void* d_ws, size_t ws_size,
                              hipStream_t stream) {
    (void)in_sizes; (void)n_in; (void)out_size;
    const float* feats_t   = (const float*)d_in[0];
    const float* feats_ref = (const float*)d_in[1];
    const float* v_t       = (const float*)d_in[2];
    const float* v_ref     = (const float*)d_in[3];
    const float* w1        = (const float*)d_in[4];  // conv1 -> K side
    const float* w2        = (const float*)d_in[6];  // conv2 -> Q side
    float* out = (float*)d_out;

    // ws: Q 1MB | Kt 4MB | Vt2 4MB | Opart (KS*2MB) | lpart ; P(f32, 8MB) aliases Opart
    const size_t opart_off = (size_t)(9u << 20);
    const size_t per_split = (size_t)NQ * CDIM * 4;            // 2MB
    const size_t need16 = opart_off + 16 * per_split + 16 * NQ * 4;
    const size_t need8  = opart_off + 8  * per_split + 8  * NQ * 4;
    if (ws_size < need8) return;

    char* ws = (char*)d_ws;
    unsigned int*   Q   = (unsigned int*)(ws);
    unsigned short* Kt  = (unsigned short*)(ws + (size_t)(1u << 20));
    unsigned short* Vt2 = (unsigned short*)(ws + (size_t)(5u << 20));
    float* Opart = (float*)(ws + opart_off);
    float* P     = Opart;   // consumed by prep_k2 before attn writes Opart

    hipLaunchKernelGGL(prep_q_kernel, dim3(1024), dim3(256), 0, stream, feats_t, v_t, w2, Q);
    hipLaunchKernelGGL(prep_p_kernel, dim3(8192), dim3(256), 0, stream, feats_ref, v_ref, P, Vt2);
    hipLaunchKernelGGL(prep_k2_kernel, dim3(4096), dim3(256), 0, stream, P, w1, (unsigned int*)Kt);

    if (ws_size >= need16) {
        float* lpart = (float*)(ws + opart_off + 16 * per_split);
        hipLaunchKernelGGL(HIP_KERNEL_NAME(attn_kernel<16>), dim3((NQ / QT) * 16), dim3(512), 0,
                           stream, (const unsigned short*)Q, Kt, Vt2, Opart, lpart);
        hipLaunchKernelGGL(HIP_KERNEL_NAME(reduce_kernel<16>), dim3(2048), dim3(256), 0,
                           stream, Opart, lpart, out);
    } else {
        float* lpart = (float*)(ws + opart_off + 8 * per_split);
        hipLaunchKernelGGL(HIP_KERNEL_NAME(attn_kernel<8>), dim3((NQ / QT) * 8), dim3(512), 0,
                           stream, (const unsigned short*)Q, Kt, Vt2, Opart, lpart);
        hipLaunchKernelGGL(HIP_KERNEL_NAME(reduce_kernel<8>), dim3(2048), dim3(256), 0,
                           stream, Opart, lpart, out);
    }
}

// Round 10
// 79.765 us; speedup vs baseline: 1.4669x; 1.1176x over previous
//
#include <hip/hip_runtime.h>
#include <stdint.h>
#include <math.h>

typedef short bf16x8 __attribute__((ext_vector_type(8)));
typedef float f32x16 __attribute__((ext_vector_type(16)));
typedef unsigned int uint4v __attribute__((ext_vector_type(4)));

#define GAS __attribute__((address_space(1)))
#define LAS __attribute__((address_space(3)))

#define CDIM 128
#define NQ   4096
#define NK   16384
#define QT   128         // queries per block (4 waves x 32)
#define KTILE 32
#define NBUF 3
#define LOG2E 1.4426950408889634f

__device__ __forceinline__ unsigned short f2bf(float f) {
    unsigned int u = __builtin_bit_cast(unsigned int, f);
    u = (u + 0x7fffu + ((u >> 16) & 1u)) >> 16;
    return (unsigned short)u;
}

__device__ __forceinline__ void gload_lds16(const void* g, void* l) {
    __builtin_amdgcn_global_load_lds((const GAS unsigned int*)g, (LAS unsigned int*)l, 16, 0, 0);
}

__device__ __forceinline__ unsigned cvtpk(float a, float b) {
    unsigned r;
    asm("v_cvt_pk_bf16_f32 %0, %1, %2" : "=v"(r) : "v"(a), "v"(b));
    return r;
}

// a' = lane<32 ? a : b[lane-32] ; b' = lane<32 ? a[lane+32] : b
__device__ __forceinline__ void swap32(unsigned& a, unsigned& b) {
    asm("v_permlane32_swap_b32 %0, %1" : "+v"(a), "+v"(b));
}

// ---------------- prep_q: Q[q][c] = bf16(log2e * conv2 (x) (feats_t * vt)) ----------------
__global__ void prep_q_kernel(const float* __restrict__ feats_t,
                              const float* __restrict__ v_t,
                              const float* __restrict__ w2,
                              unsigned int* __restrict__ Q32) {
    int idx = blockIdx.x * 256 + threadIdx.x;   // 262144 threads
    int q = idx & 4095, cp = idx >> 12;         // cp = c-pair 0..63
    int y = q >> 6, x = q & 63;
    const float* fb0 = feats_t + (size_t)(cp * 2) * 4096;
    const float* fb1 = fb0 + 4096;
    float wv[9];
#pragma unroll
    for (int i = 0; i < 9; ++i) wv[i] = w2[i];
    float acc0 = 0.f, acc1 = 0.f;
#pragma unroll
    for (int u = 0; u < 3; ++u) {
        int yy = y + u - 1;
        if ((unsigned)yy >= 64u) continue;
#pragma unroll
        for (int v = 0; v < 3; ++v) {
            int xx = x + v - 1;
            if ((unsigned)xx >= 64u) continue;
            float m = wv[u * 3 + v] * v_t[yy * 1024 + xx * 4];
            acc0 += m * fb0[yy * 64 + xx];
            acc1 += m * fb1[yy * 64 + xx];
        }
    }
    Q32[(size_t)q * 64 + cp] =
        (unsigned)f2bf(acc0 * LOG2E) | ((unsigned)f2bf(acc1 * LOG2E) << 16);
}

// ---------------- prep_p: P[c][rk] = fr*vr (f32) ; Vt2 = 32k-tiled bf16 ----------------
// Vt2 tile (32 keys, 16B chunks): chunk = jh*128 + c holds V[c][k = tile*32 + jh*8 .. +8)
__global__ void prep_p_kernel(const float* __restrict__ feats_ref,
                              const float* __restrict__ v_ref,
                              float* __restrict__ P,
                              unsigned short* __restrict__ Vt2) {
    int idx = blockIdx.x * 256 + threadIdx.x;   // 2M threads
    int c = idx >> 14, rk = idx & 16383;
    int r = rk >> 12, k4 = rk & 4095, ky = k4 >> 6, kx = k4 & 63;
    float v = feats_ref[idx] * v_ref[r * 65536 + ky * 1024 + kx * 4];
    P[idx] = v;
    Vt2[(size_t)(rk >> 5) * 4096 + (((rk >> 3) & 3) * 128 + c) * 8 + (rk & 7)] = f2bf(v);
}

// ---------------- prep_k2: Kt = 32k-tiled bf16 of conv1 (x) P ----------------
// Kt tile: chunk = cp*32 + rw holds K[rk = tile*32 + rw][c = cp*8 .. +8)
__global__ void prep_k2_kernel(const float* __restrict__ P,
                               const float* __restrict__ w1,
                               unsigned int* __restrict__ K32) {
    int idx = blockIdx.x * 256 + threadIdx.x;   // 1048576 threads
    int rk = idx & 16383, cp2 = idx >> 14;      // cp2 = c-pair 0..63
    int r = rk >> 12, k4 = rk & 4095, ky = k4 >> 6, kx = k4 & 63;
    const float* pb0 = P + (size_t)(cp2 * 2) * NK + r * 4096;
    const float* pb1 = pb0 + NK;
    float wv[9];
#pragma unroll
    for (int i = 0; i < 9; ++i) wv[i] = w1[i];
    float acc0 = 0.f, acc1 = 0.f;
#pragma unroll
    for (int u = 0; u < 3; ++u) {
        int yy = ky + u - 1;
        if ((unsigned)yy >= 64u) continue;
#pragma unroll
        for (int v = 0; v < 3; ++v) {
            int xx = kx + v - 1;
            if ((unsigned)xx >= 64u) continue;
            float w = wv[u * 3 + v];
            acc0 += w * pb0[yy * 64 + xx];
            acc1 += w * pb1[yy * 64 + xx];
        }
    }
    int tile = rk >> 5, rw = rk & 31;
    K32[(size_t)tile * 2048 + ((cp2 >> 2) * 32 + rw) * 4 + (cp2 & 3)] =
        (unsigned)f2bf(acc0) | ((unsigned)f2bf(acc1) << 16);
}

// ---- attn: 4 waves x 32q, KTILE=32, 3-buffer depth-2 prefetch, counted vmcnt ----
template<int KS>
__launch_bounds__(256, 2)
__global__ void attn_kernel(const unsigned short* __restrict__ Qg,
                            const unsigned short* __restrict__ Kt,
                            const unsigned short* __restrict__ Vt2,
                            float* __restrict__ Opart,
                            float* __restrict__ lpart) {
    constexpr int NITER = (NK / KS) / KTILE;                  // KS=16 -> 32
    __shared__ __align__(16) unsigned short KV[NBUF][2][4096]; // 48KB

    const int tid = threadIdx.x;
    const int wid = tid >> 6;
    const int lane = tid & 63;
    const int l31 = lane & 31;
    const int lh = lane >> 5;
    const int ks = blockIdx.x & (KS - 1);
    const int qt = blockIdx.x / KS;
    const int q0 = qt * QT + wid * 32;
    const int tile0 = ks * NITER;

    // Q fragments (pre-scaled by log2e): lane holds Q[q0+l31][s*16 + lh*8 + j]
    bf16x8 qf[8];
#pragma unroll
    for (int s = 0; s < 8; ++s)
        qf[s] = *(const bf16x8*)(Qg + (size_t)(q0 + l31) * CDIM + s * 16 + lh * 8);

    f32x16 accO[4];
#pragma unroll
    for (int u = 0; u < 4; ++u)
#pragma unroll
        for (int r = 0; r < 16; ++r) accO[u][r] = 0.f;
    float l_acc = 0.f;

    // staging: per tile 512 chunks K + 512 chunks V, 256 threads -> 2+2 loads/thread
#define STAGE(nb, tg)                                                             \
    do {                                                                          \
        _Pragma("unroll") for (int j = 0; j < 2; ++j) {                           \
            int mb = (wid * 2 + j) * 64;                                          \
            gload_lds16(Kt + (size_t)(tg) * 4096 + (mb + lane) * 8,               \
                        &KV[(nb)][0][mb * 8]);                                    \
            gload_lds16(Vt2 + (size_t)(tg) * 4096 + (mb + lane) * 8,              \
                        &KV[(nb)][1][mb * 8]);                                    \
        }                                                                         \
    } while (0)

    STAGE(0, tile0);
    STAGE(1, tile0 + 1);
    int bc = 0;   // buffer holding tile `it`

#pragma unroll 1
    for (int it = 0; it < NITER; ++it) {
        // counted wait: tile-it loads were issued 2 iterations ago -> usually done
        if (it + 1 < NITER)
            asm volatile("s_waitcnt vmcnt(4)" ::: "memory");
        else
            asm volatile("s_waitcnt vmcnt(0)" ::: "memory");
        __syncthreads();   // everyone's tile-it landed; prev-iter reads of stage target done
        if (it + 2 < NITER) {
            int bs = bc + 2; if (bs >= NBUF) bs -= NBUF;
            STAGE(bs, tile0 + it + 2);
        }

        // S^T[k][q]: A = K (32k x 16c slice), B = Q
        f32x16 S;
#pragma unroll
        for (int r = 0; r < 16; ++r) S[r] = 0.f;
        __builtin_amdgcn_s_setprio(1);
#pragma unroll
        for (int s = 0; s < 8; ++s) {
            bf16x8 kf = *(const bf16x8*)(&KV[bc][0][((s * 2 + lh) * 32 + l31) * 8]);
            S = __builtin_amdgcn_mfma_f32_32x32x16_bf16(kf, qf[s], S, 0, 0, 0);
        }
        __builtin_amdgcn_s_setprio(0);
        // P = exp2(S) in place (Q pre-scaled); lane holds 16 k-slots of query q0+l31
#pragma unroll
        for (int r = 0; r < 16; ++r) { S[r] = exp2f(S[r]); l_acc += S[r]; }
        // pack + redistribute into PV B-frag order (verified R5-R9 mapping)
        unsigned w0 = cvtpk(S[0], S[1]),   w1 = cvtpk(S[2], S[3]);
        unsigned w2 = cvtpk(S[4], S[5]),   w3 = cvtpk(S[6], S[7]);
        unsigned w4 = cvtpk(S[8], S[9]),   w5 = cvtpk(S[10], S[11]);
        unsigned w6 = cvtpk(S[12], S[13]), w7 = cvtpk(S[14], S[15]);
        swap32(w0, w2);
        swap32(w1, w3);
        swap32(w4, w6);
        swap32(w5, w7);
        bf16x8 pbA = __builtin_bit_cast(bf16x8, (uint4v){w0, w1, w2, w3});
        bf16x8 pbB = __builtin_bit_cast(bf16x8, (uint4v){w4, w5, w6, w7});
        // O^T += V . P^T  (A = V 32c x 16k slices; 4 independent chains)
        __builtin_amdgcn_s_setprio(1);
#pragma unroll
        for (int u = 0; u < 4; ++u) {
            bf16x8 vfa = *(const bf16x8*)(&KV[bc][1][((lh) * 128 + u * 32 + l31) * 8]);
            accO[u] = __builtin_amdgcn_mfma_f32_32x32x16_bf16(vfa, pbA, accO[u], 0, 0, 0);
            bf16x8 vfb = *(const bf16x8*)(&KV[bc][1][((2 + lh) * 128 + u * 32 + l31) * 8]);
            accO[u] = __builtin_amdgcn_mfma_f32_32x32x16_bf16(vfb, pbB, accO[u], 0, 0, 0);
        }
        __builtin_amdgcn_s_setprio(0);
        bc = bc + 1; if (bc >= NBUF) bc -= NBUF;
    }
#undef STAGE

    l_acc += __shfl_xor(l_acc, 32);
    if (lane < 32) lpart[ks * NQ + q0 + l31] = l_acc;
#pragma unroll
    for (int u = 0; u < 4; ++u)
#pragma unroll
        for (int r = 0; r < 16; ++r) {
            int c = u * 32 + (r & 3) + 8 * (r >> 2) + 4 * lh;
            Opart[((size_t)(ks * CDIM + c)) * NQ + q0 + l31] = accO[u][r];
        }
}

// ---------------- reduce: out[c][q] = sum_s Opart[s][c][q] / sum_s lpart[s][q] ----------------
template<int KS>
__global__ void reduce_kernel(const float* __restrict__ Opart,
                              const float* __restrict__ lpart,
                              float* __restrict__ out) {
    int i = blockIdx.x * 256 + threadIdx.x;
    int c = i >> 12, q = i & 4095;
    float den = 0.f, o = 0.f;
#pragma unroll
    for (int s = 0; s < KS; ++s) {
        den += lpart[s * NQ + q];
        o += Opart[((size_t)(s * CDIM + c)) * NQ + q];
    }
    out[(size_t)c * NQ + q] = o / den;
}

extern "C" void kernel_launch(void* const* d_in, const int* in_sizes, int n_in,
                              void* d_out, int out_size, void* d_ws, size_t ws_size,
                              hipStream_t stream) {
    (void)in_sizes; (void)n_in; (void)out_size;
    const float* feats_t   = (const float*)d_in[0];
    const float* feats_ref = (const float*)d_in[1];
    const float* v_t       = (const float*)d_in[2];
    const float* v_ref     = (const float*)d_in[3];
    const float* w1        = (const float*)d_in[4];  // conv1 -> K side
    const float* w2        = (const float*)d_in[6];  // conv2 -> Q side
    float* out = (float*)d_out;

    // ws: Q 1MB | Kt 4MB | Vt2 4MB | Opart (KS*2MB) | lpart ; P(f32, 8MB) aliases Opart
    const size_t opart_off = (size_t)(9u << 20);
    const size_t per_split = (size_t)NQ * CDIM * 4;            // 2MB
    const size_t need16 = opart_off + 16 * per_split + 16 * NQ * 4;
    const size_t need8  = opart_off + 8  * per_split + 8  * NQ * 4;
    if (ws_size < need8) return;

    char* ws = (char*)d_ws;
    unsigned int*   Q   = (unsigned int*)(ws);
    unsigned short* Kt  = (unsigned short*)(ws + (size_t)(1u << 20));
    unsigned short* Vt2 = (unsigned short*)(ws + (size_t)(5u << 20));
    float* Opart = (float*)(ws + opart_off);
    float* P     = Opart;   // consumed by prep_k2 before attn writes Opart

    hipLaunchKernelGGL(prep_q_kernel, dim3(1024), dim3(256), 0, stream, feats_t, v_t, w2, Q);
    hipLaunchKernelGGL(prep_p_kernel, dim3(8192), dim3(256), 0, stream, feats_ref, v_ref, P, Vt2);
    hipLaunchKernelGGL(prep_k2_kernel, dim3(4096), dim3(256), 0, stream, P, w1, (unsigned int*)Kt);

    if (ws_size >= need16) {
        float* lpart = (float*)(ws + opart_off + 16 * per_split);
        hipLaunchKernelGGL(HIP_KERNEL_NAME(attn_kernel<16>), dim3((NQ / QT) * 16), dim3(256), 0,
                           stream, (const unsigned short*)Q, Kt, Vt2, Opart, lpart);
        hipLaunchKernelGGL(HIP_KERNEL_NAME(reduce_kernel<16>), dim3(2048), dim3(256), 0,
                           stream, Opart, lpart, out);
    } else {
        float* lpart = (float*)(ws + opart_off + 8 * per_split);
        hipLaunchKernelGGL(HIP_KERNEL_NAME(attn_kernel<8>), dim3((NQ / QT) * 8), dim3(256), 0,
                           stream, (const unsigned short*)Q, Kt, Vt2, Opart, lpart);
        hipLaunchKernelGGL(HIP_KERNEL_NAME(reduce_kernel<8>), dim3(2048), dim3(256), 0,
                           stream, Opart, lpart, out);
    }
}

// Round 13
// 78.469 us; speedup vs baseline: 1.4911x; 1.0165x over previous
//
#include <hip/hip_runtime.h>
#include <stdint.h>
#include <math.h>

typedef short bf16x8 __attribute__((ext_vector_type(8)));
typedef float f32x16 __attribute__((ext_vector_type(16)));
typedef unsigned int uint4v __attribute__((ext_vector_type(4)));

#define GAS __attribute__((address_space(1)))
#define LAS __attribute__((address_space(3)))

#define CDIM 128
#define NQ   4096
#define NK   16384
#define QT   128         // queries per block (4 waves x 32)
#define KTILE 64
#define LOG2E 1.4426950408889634f

__device__ __forceinline__ unsigned short f2bf(float f) {
    unsigned int u = __builtin_bit_cast(unsigned int, f);
    u = (u + 0x7fffu + ((u >> 16) & 1u)) >> 16;
    return (unsigned short)u;
}

__device__ __forceinline__ void gload_lds16(const void* g, void* l) {
    __builtin_amdgcn_global_load_lds((const GAS unsigned int*)g, (LAS unsigned int*)l, 16, 0, 0);
}

__device__ __forceinline__ unsigned cvtpk(float a, float b) {
    unsigned r;
    asm("v_cvt_pk_bf16_f32 %0, %1, %2" : "=v"(r) : "v"(a), "v"(b));
    return r;
}

// a' = lane<32 ? a : b[lane-32] ; b' = lane<32 ? a[lane+32] : b
__device__ __forceinline__ void swap32(unsigned& a, unsigned& b) {
    asm("v_permlane32_swap_b32 %0, %1" : "+v"(a), "+v"(b));
}

// ---------------- prep_q: Q[q][c] = bf16(log2e * conv2 (x) (feats_t * vt)) ----------------
__global__ void prep_q_kernel(const float* __restrict__ feats_t,
                              const float* __restrict__ v_t,
                              const float* __restrict__ w2,
                              unsigned int* __restrict__ Q32) {
    int idx = blockIdx.x * 256 + threadIdx.x;   // 262144 threads
    int q = idx & 4095, cp = idx >> 12;         // cp = c-pair 0..63
    int y = q >> 6, x = q & 63;
    const float* fb0 = feats_t + (size_t)(cp * 2) * 4096;
    const float* fb1 = fb0 + 4096;
    float wv[9];
#pragma unroll
    for (int i = 0; i < 9; ++i) wv[i] = w2[i];
    float acc0 = 0.f, acc1 = 0.f;
#pragma unroll
    for (int u = 0; u < 3; ++u) {
        int yy = y + u - 1;
        if ((unsigned)yy >= 64u) continue;
#pragma unroll
        for (int v = 0; v < 3; ++v) {
            int xx = x + v - 1;
            if ((unsigned)xx >= 64u) continue;
            float m = wv[u * 3 + v] * v_t[yy * 1024 + xx * 4];
            acc0 += m * fb0[yy * 64 + xx];
            acc1 += m * fb1[yy * 64 + xx];
        }
    }
    Q32[(size_t)q * 64 + cp] =
        (unsigned)f2bf(acc0 * LOG2E) | ((unsigned)f2bf(acc1 * LOG2E) << 16);
}

// ---------------- prep_p: P[c][rk] = fr*vr (f32) ; Vt2 = 64k-tiled bf16 ----------------
// Vt2 tile (64 keys, 16B chunks): chunk = jh*128 + c holds V[c][k = tile*64 + jh*8 .. +8)
__global__ void prep_p_kernel(const float* __restrict__ feats_ref,
                              const float* __restrict__ v_ref,
                              float* __restrict__ P,
                              unsigned short* __restrict__ Vt2) {
    int idx = blockIdx.x * 256 + threadIdx.x;   // 2M threads
    int c = idx >> 14, rk = idx & 16383;
    int r = rk >> 12, k4 = rk & 4095, ky = k4 >> 6, kx = k4 & 63;
    float v = feats_ref[idx] * v_ref[r * 65536 + ky * 1024 + kx * 4];
    P[idx] = v;
    Vt2[(size_t)(rk >> 6) * 8192 + (((rk >> 3) & 7) * 128 + c) * 8 + (rk & 7)] = f2bf(v);
}

// ---------------- prep_k2: Kt = 64k-tiled bf16 of conv1 (x) P ----------------
// Kt tile: chunk = cp*64 + rw holds K[rk = tile*64 + rw][c = cp*8 .. +8)
__global__ void prep_k2_kernel(const float* __restrict__ P,
                               const float* __restrict__ w1,
                               unsigned int* __restrict__ K32) {
    int idx = blockIdx.x * 256 + threadIdx.x;   // 1048576 threads
    int rk = idx & 16383, cp2 = idx >> 14;      // cp2 = c-pair 0..63
    int r = rk >> 12, k4 = rk & 4095, ky = k4 >> 6, kx = k4 & 63;
    const float* pb0 = P + (size_t)(cp2 * 2) * NK + r * 4096;
    const float* pb1 = pb0 + NK;
    float wv[9];
#pragma unroll
    for (int i = 0; i < 9; ++i) wv[i] = w1[i];
    float acc0 = 0.f, acc1 = 0.f;
#pragma unroll
    for (int u = 0; u < 3; ++u) {
        int yy = ky + u - 1;
        if ((unsigned)yy >= 64u) continue;
#pragma unroll
        for (int v = 0; v < 3; ++v) {
            int xx = kx + v - 1;
            if ((unsigned)xx >= 64u) continue;
            float w = wv[u * 3 + v];
            acc0 += w * pb0[yy * 64 + xx];
            acc1 += w * pb1[yy * 64 + xx];
        }
    }
    int tile = rk >> 6, rw = rk & 63;
    K32[(size_t)tile * 4096 + ((cp2 >> 2) * 64 + rw) * 4 + (cp2 & 3)] =
        (unsigned)f2bf(acc0) | ((unsigned)f2bf(acc1) << 16);
}

// ---- attn: 4 waves x 32q, KTILE=64, 2-buffer + counted vmcnt(8), 2 barriers/64 keys ----
template<int KS>
__launch_bounds__(256, 2)
__global__ void attn_kernel(const unsigned short* __restrict__ Qg,
                            const unsigned short* __restrict__ Kt,
                            const unsigned short* __restrict__ Vt2,
                            float* __restrict__ Opart,
                            float* __restrict__ lpart) {
    constexpr int NITER = (NK / KS) / KTILE;                  // KS=16 -> 16
    __shared__ __align__(16) unsigned short KV[2][2][8192];   // [buf][K/V][16KB] = 64KB

    const int tid = threadIdx.x;
    const int wid = tid >> 6;
    const int lane = tid & 63;
    const int l31 = lane & 31;
    const int lh = lane >> 5;
    const int ks = blockIdx.x & (KS - 1);
    const int qt = blockIdx.x / KS;
    const int q0 = qt * QT + wid * 32;
    const int tile0 = ks * NITER;

    // Q fragments (pre-scaled by log2e): lane holds Q[q0+l31][s*16 + lh*8 + j]
    bf16x8 qf[8];
#pragma unroll
    for (int s = 0; s < 8; ++s)
        qf[s] = *(const bf16x8*)(Qg + (size_t)(q0 + l31) * CDIM + s * 16 + lh * 8);

    f32x16 accO[4];
#pragma unroll
    for (int u = 0; u < 4; ++u)
#pragma unroll
        for (int r = 0; r < 16; ++r) accO[u][r] = 0.f;
    float l_acc = 0.f;

    // staging: per tile 1024 chunks K + 1024 chunks V; 256 threads -> 4+4 loads/thread
#define STAGE(nb, tg)                                                             \
    do {                                                                          \
        _Pragma("unroll") for (int j = 0; j < 4; ++j) {                           \
            int mb = (wid * 4 + j) * 64;                                          \
            gload_lds16(Kt + (size_t)(tg) * 8192 + (mb + lane) * 8,               \
                        &KV[(nb)][0][mb * 8]);                                    \
            gload_lds16(Vt2 + (size_t)(tg) * 8192 + (mb + lane) * 8,              \
                        &KV[(nb)][1][mb * 8]);                                    \
        }                                                                         \
    } while (0)

    STAGE(0, tile0);

#pragma unroll 1
    for (int it = 0; it < NITER; ++it) {
        const int bc = it & 1;
        __syncthreads();   // all waves done reading buf bc^1 (iter it-1) -> safe to overwrite
        if (it + 1 < NITER) {
            STAGE(bc ^ 1, tile0 + it + 1);
            asm volatile("s_waitcnt vmcnt(8)" ::: "memory");   // tile-it loads drained
        } else {
            asm volatile("s_waitcnt vmcnt(0)" ::: "memory");
        }
        __syncthreads();   // everyone's tile-it chunks landed

        // QK^T: two independent 8-MFMA chains (key groups t=0,1)
        f32x16 S0, S1;
#pragma unroll
        for (int r = 0; r < 16; ++r) { S0[r] = 0.f; S1[r] = 0.f; }
        __builtin_amdgcn_s_setprio(1);
#pragma unroll
        for (int s = 0; s < 8; ++s) {
            bf16x8 kf0 = *(const bf16x8*)(&KV[bc][0][((s * 2 + lh) * 64 + l31) * 8]);
            S0 = __builtin_amdgcn_mfma_f32_32x32x16_bf16(kf0, qf[s], S0, 0, 0, 0);
            bf16x8 kf1 = *(const bf16x8*)(&KV[bc][0][((s * 2 + lh) * 64 + 32 + l31) * 8]);
            S1 = __builtin_amdgcn_mfma_f32_32x32x16_bf16(kf1, qf[s], S1, 0, 0, 0);
        }
        __builtin_amdgcn_s_setprio(0);

        // P = exp2(S) (libm; Q pre-scaled by log2e) -- R10-validated numerics
        float e0[16], e1[16];
#pragma unroll
        for (int r = 0; r < 16; ++r) { e0[r] = exp2f(S0[r]); l_acc += e0[r]; }
#pragma unroll
        for (int r = 0; r < 16; ++r) { e1[r] = exp2f(S1[r]); l_acc += e1[r]; }

        // pack + redistribute into PV B-frag order (verified R5-R10 mapping)
        unsigned a0 = cvtpk(e0[0], e0[1]),   a1 = cvtpk(e0[2], e0[3]);
        unsigned a2 = cvtpk(e0[4], e0[5]),   a3 = cvtpk(e0[6], e0[7]);
        unsigned a4 = cvtpk(e0[8], e0[9]),   a5 = cvtpk(e0[10], e0[11]);
        unsigned a6 = cvtpk(e0[12], e0[13]), a7 = cvtpk(e0[14], e0[15]);
        swap32(a0, a2); swap32(a1, a3); swap32(a4, a6); swap32(a5, a7);
        unsigned b0 = cvtpk(e1[0], e1[1]),   b1 = cvtpk(e1[2], e1[3]);
        unsigned b2 = cvtpk(e1[4], e1[5]),   b3 = cvtpk(e1[6], e1[7]);
        unsigned b4 = cvtpk(e1[8], e1[9]),   b5 = cvtpk(e1[10], e1[11]);
        unsigned b6 = cvtpk(e1[12], e1[13]), b7 = cvtpk(e1[14], e1[15]);
        swap32(b0, b2); swap32(b1, b3); swap32(b4, b6); swap32(b5, b7);
        bf16x8 pA0 = __builtin_bit_cast(bf16x8, (uint4v){a0, a1, a2, a3});
        bf16x8 pB0 = __builtin_bit_cast(bf16x8, (uint4v){a4, a5, a6, a7});
        bf16x8 pA1 = __builtin_bit_cast(bf16x8, (uint4v){b0, b1, b2, b3});
        bf16x8 pB1 = __builtin_bit_cast(bf16x8, (uint4v){b4, b5, b6, b7});

        // O^T += V . P^T : per u, 4-MFMA chain (t0 A/B then t1 A/B)
        __builtin_amdgcn_s_setprio(1);
#pragma unroll
        for (int u = 0; u < 4; ++u) {
            bf16x8 v0a = *(const bf16x8*)(&KV[bc][1][((lh) * 128 + u * 32 + l31) * 8]);
            accO[u] = __builtin_amdgcn_mfma_f32_32x32x16_bf16(v0a, pA0, accO[u], 0, 0, 0);
            bf16x8 v0b = *(const bf16x8*)(&KV[bc][1][((2 + lh) * 128 + u * 32 + l31) * 8]);
            accO[u] = __builtin_amdgcn_mfma_f32_32x32x16_bf16(v0b, pB0, accO[u], 0, 0, 0);
            bf16x8 v1a = *(const bf16x8*)(&KV[bc][1][((4 + lh) * 128 + u * 32 + l31) * 8]);
            accO[u] = __builtin_amdgcn_mfma_f32_32x32x16_bf16(v1a, pA1, accO[u], 0, 0, 0);
            bf16x8 v1b = *(const bf16x8*)(&KV[bc][1][((6 + lh) * 128 + u * 32 + l31) * 8]);
            accO[u] = __builtin_amdgcn_mfma_f32_32x32x16_bf16(v1b, pB1, accO[u], 0, 0, 0);
        }
        __builtin_amdgcn_s_setprio(0);
    }
#undef STAGE

    l_acc += __shfl_xor(l_acc, 32);
    if (lane < 32) lpart[ks * NQ + q0 + l31] = l_acc;
#pragma unroll
    for (int u = 0; u < 4; ++u)
#pragma unroll
        for (int r = 0; r < 16; ++r) {
            int c = u * 32 + (r & 3) + 8 * (r >> 2) + 4 * lh;
            Opart[((size_t)(ks * CDIM + c)) * NQ + q0 + l31] = accO[u][r];
        }
}

// ---------------- reduce: out[c][q] = sum_s Opart[s][c][q] / sum_s lpart[s][q] ----------------
template<int KS>
__global__ void reduce_kernel(const float* __restrict__ Opart,
                              const float* __restrict__ lpart,
                              float* __restrict__ out) {
    int i = blockIdx.x * 256 + threadIdx.x;
    int c = i >> 12, q = i & 4095;
    float den = 0.f, o = 0.f;
#pragma unroll
    for (int s = 0; s < KS; ++s) {
        den += lpart[s * NQ + q];
        o += Opart[((size_t)(s * CDIM + c)) * NQ + q];
    }
    out[(size_t)c * NQ + q] = o / den;
}

extern "C" void kernel_launch(void* const* d_in, const int* in_sizes, int n_in,
                              void* d_out, int out_size, void* d_ws, size_t ws_size,
                              hipStream_t stream) {
    (void)in_sizes; (void)n_in; (void)out_size;
    const float* feats_t   = (const float*)d_in[0];
    const float* feats_ref = (const float*)d_in[1];
    const float* v_t       = (const float*)d_in[2];
    const float* v_ref     = (const float*)d_in[3];
    const float* w1        = (const float*)d_in[4];  // conv1 -> K side
    const float* w2        = (const float*)d_in[6];  // conv2 -> Q side
    float* out = (float*)d_out;

    // ws: Q 1MB | Kt 4MB | Vt2 4MB | Opart (KS*2MB) | lpart ; P(f32, 8MB) aliases Opart
    const size_t opart_off = (size_t)(9u << 20);
    const size_t per_split = (size_t)NQ * CDIM * 4;            // 2MB
    const size_t need16 = opart_off + 16 * per_split + 16 * NQ * 4;
    const size_t need8  = opart_off + 8  * per_split + 8  * NQ * 4;
    if (ws_size < need8) return;

    char* ws = (char*)d_ws;
    unsigned int*   Q   = (unsigned int*)(ws);
    unsigned short* Kt  = (unsigned short*)(ws + (size_t)(1u << 20));
    unsigned short* Vt2 = (unsigned short*)(ws + (size_t)(5u << 20));
    float* Opart = (float*)(ws + opart_off);
    float* P     = Opart;   // consumed by prep_k2 before attn writes Opart

    hipLaunchKernelGGL(prep_q_kernel, dim3(1024), dim3(256), 0, stream, feats_t, v_t, w2, Q);
    hipLaunchKernelGGL(prep_p_kernel, dim3(8192), dim3(256), 0, stream, feats_ref, v_ref, P, Vt2);
    hipLaunchKernelGGL(prep_k2_kernel, dim3(4096), dim3(256), 0, stream, P, w1, (unsigned int*)Kt);

    if (ws_size >= need16) {
        float* lpart = (float*)(ws + opart_off + 16 * per_split);
        hipLaunchKernelGGL(HIP_KERNEL_NAME(attn_kernel<16>), dim3((NQ / QT) * 16), dim3(256), 0,
                           stream, (const unsigned short*)Q, Kt, Vt2, Opart, lpart);
        hipLaunchKernelGGL(HIP_KERNEL_NAME(reduce_kernel<16>), dim3(2048), dim3(256), 0,
                           stream, Opart, lpart, out);
    } else {
        float* lpart = (float*)(ws + opart_off + 8 * per_split);
        hipLaunchKernelGGL(HIP_KERNEL_NAME(attn_kernel<8>), dim3((NQ / QT) * 8), dim3(256), 0,
                           stream, (const unsigned short*)Q, Kt, Vt2, Opart, lpart);
        hipLaunchKernelGGL(HIP_KERNEL_NAME(reduce_kernel<8>), dim3(2048), dim3(256), 0,
                           stream, Opart, lpart, out);
    }
}

// Round 14
// 74.389 us; speedup vs baseline: 1.5729x; 1.0548x over previous
//
#include <hip/hip_runtime.h>
#include <stdint.h>
#include <math.h>

typedef short bf16x8 __attribute__((ext_vector_type(8)));
typedef float f32x16 __attribute__((ext_vector_type(16)));
typedef unsigned int uint4v __attribute__((ext_vector_type(4)));

#define GAS __attribute__((address_space(1)))
#define LAS __attribute__((address_space(3)))

#define CDIM 128
#define NQ   4096
#define NK   16384
#define QT   128         // queries per block (4 waves x 32)
#define KTILE 64

__device__ __forceinline__ unsigned short f2bf(float f) {
    unsigned int u = __builtin_bit_cast(unsigned int, f);
    u = (u + 0x7fffu + ((u >> 16) & 1u)) >> 16;
    return (unsigned short)u;
}

__device__ __forceinline__ void gload_lds16(const void* g, void* l) {
    __builtin_amdgcn_global_load_lds((const GAS unsigned int*)g, (LAS unsigned int*)l, 16, 0, 0);
}

__device__ __forceinline__ unsigned cvtpk(float a, float b) {
    unsigned r;
    asm("v_cvt_pk_bf16_f32 %0, %1, %2" : "=v"(r) : "v"(a), "v"(b));
    return r;
}

// a' = lane<32 ? a : b[lane-32] ; b' = lane<32 ? a[lane+32] : b
__device__ __forceinline__ void swap32(unsigned& a, unsigned& b) {
    asm("v_permlane32_swap_b32 %0, %1" : "+v"(a), "+v"(b));
}

// ---------------- prep_q: Q[q][c] = bf16(conv2 (x) (feats_t * vt)) ----------------
__global__ void prep_q_kernel(const float* __restrict__ feats_t,
                              const float* __restrict__ v_t,
                              const float* __restrict__ w2,
                              unsigned int* __restrict__ Q32) {
    int idx = blockIdx.x * 256 + threadIdx.x;   // 262144 threads
    int q = idx & 4095, cp = idx >> 12;         // cp = c-pair 0..63
    int y = q >> 6, x = q & 63;
    const float* fb0 = feats_t + (size_t)(cp * 2) * 4096;
    const float* fb1 = fb0 + 4096;
    float wv[9];
#pragma unroll
    for (int i = 0; i < 9; ++i) wv[i] = w2[i];
    float acc0 = 0.f, acc1 = 0.f;
#pragma unroll
    for (int u = 0; u < 3; ++u) {
        int yy = y + u - 1;
        if ((unsigned)yy >= 64u) continue;
#pragma unroll
        for (int v = 0; v < 3; ++v) {
            int xx = x + v - 1;
            if ((unsigned)xx >= 64u) continue;
            float m = wv[u * 3 + v] * v_t[yy * 1024 + xx * 4];
            acc0 += m * fb0[yy * 64 + xx];
            acc1 += m * fb1[yy * 64 + xx];
        }
    }
    Q32[(size_t)q * 64 + cp] = (unsigned)f2bf(acc0) | ((unsigned)f2bf(acc1) << 16);
}

// ---------------- prep_p: P[c][rk] = fr*vr (f32) ; Vt2 = 64k-tiled bf16 ----------------
// Vt2 tile (64 keys, 16B chunks): chunk = jh*128 + c holds V[c][k = tile*64 + jh*8 .. +8)
__global__ void prep_p_kernel(const float* __restrict__ feats_ref,
                              const float* __restrict__ v_ref,
                              float* __restrict__ P,
                              unsigned short* __restrict__ Vt2) {
    int idx = blockIdx.x * 256 + threadIdx.x;   // 2M threads
    int c = idx >> 14, rk = idx & 16383;
    int r = rk >> 12, k4 = rk & 4095, ky = k4 >> 6, kx = k4 & 63;
    float v = feats_ref[idx] * v_ref[r * 65536 + ky * 1024 + kx * 4];
    P[idx] = v;
    Vt2[(size_t)(rk >> 6) * 8192 + (((rk >> 3) & 7) * 128 + c) * 8 + (rk & 7)] = f2bf(v);
}

// ---------------- prep_k2: Kt = 64k-tiled bf16 of conv1 (x) P ----------------
// Kt tile: chunk = cp*64 + rw holds K[rk = tile*64 + rw][c = cp*8 .. +8)
__global__ void prep_k2_kernel(const float* __restrict__ P,
                               const float* __restrict__ w1,
                               unsigned int* __restrict__ K32) {
    int idx = blockIdx.x * 256 + threadIdx.x;   // 1048576 threads
    int rk = idx & 16383, cp2 = idx >> 14;      // cp2 = c-pair 0..63
    int r = rk >> 12, k4 = rk & 4095, ky = k4 >> 6, kx = k4 & 63;
    const float* pb0 = P + (size_t)(cp2 * 2) * NK + r * 4096;
    const float* pb1 = pb0 + NK;
    float wv[9];
#pragma unroll
    for (int i = 0; i < 9; ++i) wv[i] = w1[i];
    float acc0 = 0.f, acc1 = 0.f;
#pragma unroll
    for (int u = 0; u < 3; ++u) {
        int yy = ky + u - 1;
        if ((unsigned)yy >= 64u) continue;
#pragma unroll
        for (int v = 0; v < 3; ++v) {
            int xx = kx + v - 1;
            if ((unsigned)xx >= 64u) continue;
            float w = wv[u * 3 + v];
            acc0 += w * pb0[yy * 64 + xx];
            acc1 += w * pb1[yy * 64 + xx];
        }
    }
    int tile = rk >> 6, rw = rk & 63;
    K32[(size_t)tile * 4096 + ((cp2 >> 2) * 64 + rw) * 4 + (cp2 & 3)] =
        (unsigned)f2bf(acc0) | ((unsigned)f2bf(acc1) << 16);
}

// ---- attn: 4 waves x 32q, KTILE=64, 2-buffer + counted vmcnt(8), phase-overlapped ----
template<int KS>
__launch_bounds__(256, 2)
__global__ void attn_kernel(const unsigned short* __restrict__ Qg,
                            const unsigned short* __restrict__ Kt,
                            const unsigned short* __restrict__ Vt2,
                            float* __restrict__ Opart,
                            float* __restrict__ lpart) {
    constexpr int NITER = (NK / KS) / KTILE;                  // KS=16 -> 16
    __shared__ __align__(16) unsigned short KV[2][2][8192];   // [buf][K/V][16KB] = 64KB

    const int tid = threadIdx.x;
    const int wid = tid >> 6;
    const int lane = tid & 63;
    const int l31 = lane & 31;
    const int lh = lane >> 5;
    const int ks = blockIdx.x & (KS - 1);
    const int qt = blockIdx.x / KS;
    const int q0 = qt * QT + wid * 32;
    const int tile0 = ks * NITER;

    // Q fragments: lane holds Q[q0+l31][s*16 + lh*8 + j]
    bf16x8 qf[8];
#pragma unroll
    for (int s = 0; s < 8; ++s)
        qf[s] = *(const bf16x8*)(Qg + (size_t)(q0 + l31) * CDIM + s * 16 + lh * 8);

    f32x16 accO[4];
#pragma unroll
    for (int u = 0; u < 4; ++u)
#pragma unroll
        for (int r = 0; r < 16; ++r) accO[u][r] = 0.f;
    float l_acc = 0.f;

    // staging: per tile 1024 chunks K + 1024 chunks V; 256 threads -> 4+4 loads/thread
#define STAGE(nb, tg)                                                             \
    do {                                                                          \
        _Pragma("unroll") for (int j = 0; j < 4; ++j) {                           \
            int mb = (wid * 4 + j) * 64;                                          \
            gload_lds16(Kt + (size_t)(tg) * 8192 + (mb + lane) * 8,               \
                        &KV[(nb)][0][mb * 8]);                                    \
            gload_lds16(Vt2 + (size_t)(tg) * 8192 + (mb + lane) * 8,              \
                        &KV[(nb)][1][mb * 8]);                                    \
        }                                                                         \
    } while (0)

    STAGE(0, tile0);

#pragma unroll 1
    for (int it = 0; it < NITER; ++it) {
        const int bc = it & 1;
        __syncthreads();   // all waves done reading buf bc^1 (iter it-1) -> safe to overwrite
        if (it + 1 < NITER) {
            STAGE(bc ^ 1, tile0 + it + 1);
            asm volatile("s_waitcnt vmcnt(8)" ::: "memory");   // tile-it loads drained
        } else {
            asm volatile("s_waitcnt vmcnt(0)" ::: "memory");
        }
        __syncthreads();   // everyone's tile-it chunks landed

        // ---- S0 chain (keys 0..31) ----
        f32x16 S0, S1;
#pragma unroll
        for (int r = 0; r < 16; ++r) { S0[r] = 0.f; S1[r] = 0.f; }
        __builtin_amdgcn_s_setprio(1);
#pragma unroll
        for (int s = 0; s < 8; ++s) {
            bf16x8 kf0 = *(const bf16x8*)(&KV[bc][0][((s * 2 + lh) * 64 + l31) * 8]);
            S0 = __builtin_amdgcn_mfma_f32_32x32x16_bf16(kf0, qf[s], S0, 0, 0, 0);
        }
        // ---- S1 chain (keys 32..63); e0-softmax VALU can overlap here ----
#pragma unroll
        for (int s = 0; s < 8; ++s) {
            bf16x8 kf1 = *(const bf16x8*)(&KV[bc][0][((s * 2 + lh) * 64 + 32 + l31) * 8]);
            S1 = __builtin_amdgcn_mfma_f32_32x32x16_bf16(kf1, qf[s], S1, 0, 0, 0);
        }
        __builtin_amdgcn_s_setprio(0);

        // ---- softmax group 0 (native exp) + pack ----
        float e0[16];
#pragma unroll
        for (int r = 0; r < 16; ++r) e0[r] = __expf(S0[r]);
        {
            float t0 = (e0[0] + e0[1]) + (e0[2] + e0[3]);
            float t1 = (e0[4] + e0[5]) + (e0[6] + e0[7]);
            float t2 = (e0[8] + e0[9]) + (e0[10] + e0[11]);
            float t3 = (e0[12] + e0[13]) + (e0[14] + e0[15]);
            l_acc += (t0 + t1) + (t2 + t3);
        }
        unsigned a0 = cvtpk(e0[0], e0[1]),   a1 = cvtpk(e0[2], e0[3]);
        unsigned a2 = cvtpk(e0[4], e0[5]),   a3 = cvtpk(e0[6], e0[7]);
        unsigned a4 = cvtpk(e0[8], e0[9]),   a5 = cvtpk(e0[10], e0[11]);
        unsigned a6 = cvtpk(e0[12], e0[13]), a7 = cvtpk(e0[14], e0[15]);
        swap32(a0, a2); swap32(a1, a3); swap32(a4, a6); swap32(a5, a7);
        bf16x8 pA0 = __builtin_bit_cast(bf16x8, (uint4v){a0, a1, a2, a3});
        bf16x8 pB0 = __builtin_bit_cast(bf16x8, (uint4v){a4, a5, a6, a7});

        // ---- PV group 0; e1-softmax VALU can overlap here ----
        __builtin_amdgcn_s_setprio(1);
#pragma unroll
        for (int u = 0; u < 4; ++u) {
            bf16x8 v0a = *(const bf16x8*)(&KV[bc][1][((lh) * 128 + u * 32 + l31) * 8]);
            accO[u] = __builtin_amdgcn_mfma_f32_32x32x16_bf16(v0a, pA0, accO[u], 0, 0, 0);
            bf16x8 v0b = *(const bf16x8*)(&KV[bc][1][((2 + lh) * 128 + u * 32 + l31) * 8]);
            accO[u] = __builtin_amdgcn_mfma_f32_32x32x16_bf16(v0b, pB0, accO[u], 0, 0, 0);
        }
        __builtin_amdgcn_s_setprio(0);

        // ---- softmax group 1 + pack ----
        float e1[16];
#pragma unroll
        for (int r = 0; r < 16; ++r) e1[r] = __expf(S1[r]);
        {
            float t0 = (e1[0] + e1[1]) + (e1[2] + e1[3]);
            float t1 = (e1[4] + e1[5]) + (e1[6] + e1[7]);
            float t2 = (e1[8] + e1[9]) + (e1[10] + e1[11]);
            float t3 = (e1[12] + e1[13]) + (e1[14] + e1[15]);
            l_acc += (t0 + t1) + (t2 + t3);
        }
        unsigned b0 = cvtpk(e1[0], e1[1]),   b1 = cvtpk(e1[2], e1[3]);
        unsigned b2 = cvtpk(e1[4], e1[5]),   b3 = cvtpk(e1[6], e1[7]);
        unsigned b4 = cvtpk(e1[8], e1[9]),   b5 = cvtpk(e1[10], e1[11]);
        unsigned b6 = cvtpk(e1[12], e1[13]), b7 = cvtpk(e1[14], e1[15]);
        swap32(b0, b2); swap32(b1, b3); swap32(b4, b6); swap32(b5, b7);
        bf16x8 pA1 = __builtin_bit_cast(bf16x8, (uint4v){b0, b1, b2, b3});
        bf16x8 pB1 = __builtin_bit_cast(bf16x8, (uint4v){b4, b5, b6, b7});

        // ---- PV group 1 ----
        __builtin_amdgcn_s_setprio(1);
#pragma unroll
        for (int u = 0; u < 4; ++u) {
            bf16x8 v1a = *(const bf16x8*)(&KV[bc][1][((4 + lh) * 128 + u * 32 + l31) * 8]);
            accO[u] = __builtin_amdgcn_mfma_f32_32x32x16_bf16(v1a, pA1, accO[u], 0, 0, 0);
            bf16x8 v1b = *(const bf16x8*)(&KV[bc][1][((6 + lh) * 128 + u * 32 + l31) * 8]);
            accO[u] = __builtin_amdgcn_mfma_f32_32x32x16_bf16(v1b, pB1, accO[u], 0, 0, 0);
        }
        __builtin_amdgcn_s_setprio(0);
    }
#undef STAGE

    l_acc += __shfl_xor(l_acc, 32);
    if (lane < 32) lpart[ks * NQ + q0 + l31] = l_acc;
#pragma unroll
    for (int u = 0; u < 4; ++u)
#pragma unroll
        for (int r = 0; r < 16; ++r) {
            int c = u * 32 + (r & 3) + 8 * (r >> 2) + 4 * lh;
            Opart[((size_t)(ks * CDIM + c)) * NQ + q0 + l31] = accO[u][r];
        }
}

// ---------------- reduce: out[c][q] = sum_s Opart[s][c][q] / sum_s lpart[s][q] ----------------
template<int KS>
__global__ void reduce_kernel(const float* __restrict__ Opart,
                              const float* __restrict__ lpart,
                              float* __restrict__ out) {
    int i = blockIdx.x * 256 + threadIdx.x;
    int c = i >> 12, q = i & 4095;
    float den = 0.f, o = 0.f;
#pragma unroll
    for (int s = 0; s < KS; ++s) {
        den += lpart[s * NQ + q];
        o += Opart[((size_t)(s * CDIM + c)) * NQ + q];
    }
    out[(size_t)c * NQ + q] = o / den;
}

extern "C" void kernel_launch(void* const* d_in, const int* in_sizes, int n_in,
                              void* d_out, int out_size, void* d_ws, size_t ws_size,
                              hipStream_t stream) {
    (void)in_sizes; (void)n_in; (void)out_size;
    const float* feats_t   = (const float*)d_in[0];
    const float* feats_ref = (const float*)d_in[1];
    const float* v_t       = (const float*)d_in[2];
    const float* v_ref     = (const float*)d_in[3];
    const float* w1        = (const float*)d_in[4];  // conv1 -> K side
    const float* w2        = (const float*)d_in[6];  // conv2 -> Q side
    float* out = (float*)d_out;

    // ws: Q 1MB | Kt 4MB | Vt2 4MB | Opart (KS*2MB) | lpart ; P(f32, 8MB) aliases Opart
    const size_t opart_off = (size_t)(9u << 20);
    const size_t per_split = (size_t)NQ * CDIM * 4;            // 2MB
    const size_t need16 = opart_off + 16 * per_split + 16 * NQ * 4;
    const size_t need8  = opart_off + 8  * per_split + 8  * NQ * 4;
    if (ws_size < need8) return;

    char* ws = (char*)d_ws;
    unsigned int*   Q   = (unsigned int*)(ws);
    unsigned short* Kt  = (unsigned short*)(ws + (size_t)(1u << 20));
    unsigned short* Vt2 = (unsigned short*)(ws + (size_t)(5u << 20));
    float* Opart = (float*)(ws + opart_off);
    float* P     = Opart;   // consumed by prep_k2 before attn writes Opart

    hipLaunchKernelGGL(prep_q_kernel, dim3(1024), dim3(256), 0, stream, feats_t, v_t, w2, Q);
    hipLaunchKernelGGL(prep_p_kernel, dim3(8192), dim3(256), 0, stream, feats_ref, v_ref, P, Vt2);
    hipLaunchKernelGGL(prep_k2_kernel, dim3(4096), dim3(256), 0, stream, P, w1, (unsigned int*)Kt);

    if (ws_size >= need16) {
        float* lpart = (float*)(ws + opart_off + 16 * per_split);
        hipLaunchKernelGGL(HIP_KERNEL_NAME(attn_kernel<16>), dim3((NQ / QT) * 16), dim3(256), 0,
                           stream, (const unsigned short*)Q, Kt, Vt2, Opart, lpart);
        hipLaunchKernelGGL(HIP_KERNEL_NAME(reduce_kernel<16>), dim3(2048), dim3(256), 0,
                           stream, Opart, lpart, out);
    } else {
        float* lpart = (float*)(ws + opart_off + 8 * per_split);
        hipLaunchKernelGGL(HIP_KERNEL_NAME(attn_kernel<8>), dim3((NQ / QT) * 8), dim3(256), 0,
                           stream, (const unsigned short*)Q, Kt, Vt2, Opart, lpart);
        hipLaunchKernelGGL(HIP_KERNEL_NAME(reduce_kernel<8>), dim3(2048), dim3(256), 0,
                           stream, Opart, lpart, out);
    }
}